// Round 4
// baseline (100.021 us; speedup 1.0000x reference)
//
#include <hip/hip_runtime.h>
#include <hip/hip_bf16.h>

typedef unsigned int u32;
typedef unsigned short u16;
typedef unsigned char u8;
typedef _Float16 f16;
typedef __attribute__((ext_vector_type(2)))  _Float16 f16x2;
typedef __attribute__((ext_vector_type(8)))  _Float16 f16x8;
typedef __attribute__((ext_vector_type(16))) _Float16 f16x16;
typedef __attribute__((ext_vector_type(4))) float f32x4;

#define NSLOT   71
#define NCARD   71
#define ONEHOT  5041     // 71*71
#define INDIM   5048     // 71*71 + 7
#define D0      512
#define D1      256
#define D2      128
#define NACT    9

__device__ __forceinline__ u16 f2h_bits(float x) { f16 h = (f16)x; u16 r; __builtin_memcpy(&r, &h, 2); return r; }

// ---------------- prep: W0 -> f16, W1 -> W1T f16 (N x K), W2 -> W2T f16 ----------------
__global__ void prep_kernel(const float* __restrict__ W0, const float* __restrict__ W1,
                            const float* __restrict__ W2,
                            u16* __restrict__ W0h, u16* __restrict__ W1T, u16* __restrict__ W2T) {
    int i = blockIdx.x * 256 + threadIdx.x;
    const int n0 = INDIM * D0;      // 2,584,576
    const int n1 = D0 * D1;         // 131,072
    const int n2 = D1 * D2;         // 32,768
    if (i < n0) {
        W0h[i] = f2h_bits(W0[i]);
    } else if (i < n0 + n1) {
        int j = i - n0; int n = j >> 9, k = j & 511;     // W1T[n][k] = W1[k][n]
        W1T[j] = f2h_bits(W1[k * D1 + n]);
    } else if (i < n0 + n1 + n2) {
        int j = i - n0 - n1; int n = j >> 8, k = j & 255; // W2T[n][k] = W2[k][n]
        W2T[j] = f2h_bits(W2[k * D2 + n]);
    }
}

// ---------------- layer 0: gather-sum one-hot rows + trump + b0, ReLU, write h0 f16 ----------------
// grid: 256 blocks; col-tile is the SLOW index (blocks 0..63 -> ct0) so each XCD's L2
// holds one 1.3MB W0 col-slice. 512 threads = 64 rowgrp x 8 colgrp, 4 rows/thread.
// LDS padded >80KB to force exactly 1 block/CU (R3 showed 2 blocks/CU thrashes L1/L2).
__global__ __launch_bounds__(512)
void layer0_kernel(const int* __restrict__ sidx, const float* __restrict__ trump,
                   const float* __restrict__ b0, const u16* __restrict__ W0h,
                   u16* __restrict__ h0) {
    __shared__ u8 idxl[256 * NSLOT];     // [row][slot]
    __shared__ float trl[256 * 7];       // [row][t]
    __shared__ u8 ldspad[65536];         // occupancy limiter: 1 block/CU
    const int tid = threadIdx.x;
    const int ct = blockIdx.x >> 6;          // 0..3  (slow)
    const int chunk = blockIdx.x & 63;       // 0..63 (fast)
    const int rbase = chunk * 256;

    if (sidx[0] == 0x7fffffff) {             // never true; keeps ldspad allocated
        ldspad[tid] = 1; __syncthreads(); h0[tid] = ldspad[tid ^ 1];
    }

    for (int i = tid; i < 256 * NSLOT; i += 512) {      // coalesced: i = r*71+s
        int v = sidx[rbase * NSLOT + i];
        v = v < 0 ? 0 : (v > NCARD - 1 ? NCARD - 1 : v);
        idxl[i] = (u8)v;
    }
    for (int i = tid; i < 256 * 7; i += 512)
        trl[i] = trump[rbase * 7 + i];
    __syncthreads();

    const int rg = tid >> 3;                 // 0..63
    const int cg = tid & 7;                  // 0..7
    const int c0 = ct * 128 + cg * 16;       // col offset in [0,512)

    f16x16 acc[4];
    {   // init with b0 + trump tail (rows 5041..5047 of W0)
        f16x16 bias;
        #pragma unroll
        for (int j = 0; j < 16; ++j) bias[j] = (f16)b0[c0 + j];
        #pragma unroll
        for (int i = 0; i < 4; ++i) acc[i] = bias;
        #pragma unroll
        for (int t = 0; t < 7; ++t) {
            f16x16 wv = *(const f16x16*)(W0h + (size_t)(ONEHOT + t) * D0 + c0);
            #pragma unroll
            for (int i = 0; i < 4; ++i)
                acc[i] += wv * (f16)trl[(rg * 4 + i) * 7 + t];
        }
    }

    for (int s = 0; s < NSLOT; ++s) {
        const u16* base = W0h + (size_t)s * NCARD * D0 + c0;
        #pragma unroll
        for (int i = 0; i < 4; ++i) {
            int card = idxl[(rg * 4 + i) * NSLOT + s];
            f16x16 wv = *(const f16x16*)(base + ((u32)card << 9));
            acc[i] += wv;                    // 8x v_pk_add_f16
        }
    }

    const f16x16 zero = {};
    #pragma unroll
    for (int i = 0; i < 4; ++i) {
        int row = rbase + rg * 4 + i;
        f16x16 v = __builtin_elementwise_max(acc[i], zero);   // ReLU, packed
        uint4* dst = (uint4*)(h0 + (size_t)row * D0 + c0);
        dst[0] = ((const uint4*)&v)[0];
        dst[1] = ((const uint4*)&v)[1];
    }
}

// ---------------- layers 1,2,p fused: per-block 32 rows, MFMA 16x16x32 f16 ----------------
// grid: 512 blocks x 512 threads (8 waves).  LDS < 64KB.
__global__ __launch_bounds__(512)
void mlp_kernel(const u16* __restrict__ h0, const u16* __restrict__ W1T, const u16* __restrict__ W2T,
                const float* __restrict__ b1, const float* __restrict__ b2,
                const float* __restrict__ Wp, const float* __restrict__ bp,
                const int* __restrict__ legal, float* __restrict__ out) {
    __shared__ u16 Abuf[32 * 520];          // h0 tile, pad 8 (row 1040B)
    __shared__ u16 h1buf[32 * 264];         // pad 8 (528B)
    __shared__ u16 h2buf[32 * 136];         // pad 8 (272B)
    __shared__ float wpb[D2 * NACT + NACT]; // Wp + bp
    const int tid = threadIdx.x;
    const int r0 = blockIdx.x * 32;

    for (int i = tid; i < 2048; i += 512) {             // 32 rows x 64 uint4
        int r = i >> 6, g = i & 63;
        uint4 v = *(const uint4*)(h0 + (size_t)(r0 + r) * D0 + g * 8);
        *(uint4*)&Abuf[r * 520 + g * 8] = v;
    }
    for (int i = tid; i < D2 * NACT + NACT; i += 512)
        wpb[i] = (i < D2 * NACT) ? Wp[i] : bp[i - D2 * NACT];
    __syncthreads();

    const int w  = tid >> 6;     // wave 0..7
    const int l  = tid & 63;
    const int lc = l & 15;       // A row / B col / D col within 16-frag
    const int kg = l >> 4;       // 0..3

    // ---- layer 1: (32x512) @ (512x256), waves split N into 8 x 32 ----
    {
        const int n0 = w * 32;
        f32x4 a00 = {0.f,0.f,0.f,0.f}, a01 = a00, a10 = a00, a11 = a00;
        for (int kb = 0; kb < D0; kb += 32) {
            f16x8 av0 = *(const f16x8*)&Abuf[lc * 520 + kb + kg * 8];
            f16x8 av1 = *(const f16x8*)&Abuf[(lc + 16) * 520 + kb + kg * 8];
            f16x8 bv0 = *(const f16x8*)(W1T + (size_t)(n0 + lc) * D0 + kb + kg * 8);
            f16x8 bv1 = *(const f16x8*)(W1T + (size_t)(n0 + 16 + lc) * D0 + kb + kg * 8);
            a00 = __builtin_amdgcn_mfma_f32_16x16x32_f16(av0, bv0, a00, 0, 0, 0);
            a01 = __builtin_amdgcn_mfma_f32_16x16x32_f16(av0, bv1, a01, 0, 0, 0);
            a10 = __builtin_amdgcn_mfma_f32_16x16x32_f16(av1, bv0, a10, 0, 0, 0);
            a11 = __builtin_amdgcn_mfma_f32_16x16x32_f16(av1, bv1, a11, 0, 0, 0);
        }
        #pragma unroll
        for (int nb = 0; nb < 2; ++nb) {
            int col = n0 + nb * 16 + lc;
            float bias = b1[col];
            #pragma unroll
            for (int j = 0; j < 4; ++j) {
                f32x4 v0 = nb ? a01 : a00;
                f32x4 v1 = nb ? a11 : a10;
                h1buf[(kg * 4 + j) * 264 + col]        = f2h_bits(fmaxf(v0[j] + bias, 0.f));
                h1buf[(16 + kg * 4 + j) * 264 + col]   = f2h_bits(fmaxf(v1[j] + bias, 0.f));
            }
        }
    }
    __syncthreads();

    // ---- layer 2: (32x256) @ (256x128), waves split N into 8 x 16 ----
    {
        const int n0 = w * 16;
        f32x4 c0 = {0.f,0.f,0.f,0.f}, c1 = c0;
        for (int kb = 0; kb < D1; kb += 32) {
            f16x8 av0 = *(const f16x8*)&h1buf[lc * 264 + kb + kg * 8];
            f16x8 av1 = *(const f16x8*)&h1buf[(lc + 16) * 264 + kb + kg * 8];
            f16x8 bv  = *(const f16x8*)(W2T + (size_t)(n0 + lc) * D1 + kb + kg * 8);
            c0 = __builtin_amdgcn_mfma_f32_16x16x32_f16(av0, bv, c0, 0, 0, 0);
            c1 = __builtin_amdgcn_mfma_f32_16x16x32_f16(av1, bv, c1, 0, 0, 0);
        }
        int col = n0 + lc;
        float bias = b2[col];
        #pragma unroll
        for (int j = 0; j < 4; ++j) {
            h2buf[(kg * 4 + j) * 136 + col]      = f2h_bits(fmaxf(c0[j] + bias, 0.f));
            h2buf[(16 + kg * 4 + j) * 136 + col] = f2h_bits(fmaxf(c1[j] + bias, 0.f));
        }
    }
    __syncthreads();

    // ---- layer p + log_softmax: 128 threads, 4 threads per row (K split 4x32) ----
    if (tid < 128) {
        int r = tid >> 2, q = tid & 3;
        float part[NACT];
        #pragma unroll
        for (int a = 0; a < NACT; ++a) part[a] = 0.f;
        int kbase = q * 32;
        #pragma unroll
        for (int kk = 0; kk < 32; kk += 2) {
            u32 pr = *(const u32*)&h2buf[r * 136 + kbase + kk];
            f16x2 hp; __builtin_memcpy(&hp, &pr, 4);
            float x0 = (float)hp.x, x1 = (float)hp.y;
            #pragma unroll
            for (int a = 0; a < NACT; ++a)
                part[a] += x0 * wpb[(kbase + kk) * NACT + a] + x1 * wpb[(kbase + kk + 1) * NACT + a];
        }
        #pragma unroll
        for (int a = 0; a < NACT; ++a) {
            part[a] += __shfl_xor(part[a], 1, 64);
            part[a] += __shfl_xor(part[a], 2, 64);
        }
        if (q == 0) {
            int row = r0 + r;
            const int* mk = legal + (size_t)row * NACT;   // bool uploaded as 4-byte; nonzero = legal
            float lg[NACT]; float mx = -INFINITY;
            #pragma unroll
            for (int a = 0; a < NACT; ++a) {
                lg[a] = part[a] + wpb[D2 * NACT + a];
                if (mk[a] != 0 && lg[a] > mx) mx = lg[a];
            }
            float s = 0.f;
            #pragma unroll
            for (int a = 0; a < NACT; ++a) if (mk[a] != 0) s += __expf(lg[a] - mx);
            float lse = mx + __logf(s);
            #pragma unroll
            for (int a = 0; a < NACT; ++a)
                out[(size_t)row * NACT + a] = (mk[a] != 0) ? (lg[a] - lse) : -INFINITY;
        }
    }
}

extern "C" void kernel_launch(void* const* d_in, const int* in_sizes, int n_in,
                              void* d_out, int out_size, void* d_ws, size_t ws_size,
                              hipStream_t stream) {
    const int*   sidx  = (const int*)d_in[0];
    const float* trump = (const float*)d_in[1];
    const int*   legal = (const int*)d_in[2];
    const float* W0 = (const float*)d_in[3];
    const float* b0 = (const float*)d_in[4];
    const float* W1 = (const float*)d_in[5];
    const float* b1 = (const float*)d_in[6];
    const float* W2 = (const float*)d_in[7];
    const float* b2 = (const float*)d_in[8];
    const float* Wp = (const float*)d_in[9];
    const float* bp = (const float*)d_in[10];
    float* out = (float*)d_out;

    // ws layout (f16 elements): W0h | W1T | W2T | h0   -> 22.3 MB total
    u16* W0h  = (u16*)d_ws;
    u16* W1T  = W0h + (size_t)INDIM * D0;
    u16* W2T  = W1T + (size_t)D0 * D1;
    u16* h0   = W2T + (size_t)D1 * D2;

    const int total = INDIM * D0 + D0 * D1 + D1 * D2;   // 2,748,416
    prep_kernel<<<(total + 255) / 256, 256, 0, stream>>>(W0, W1, W2, W0h, W1T, W2T);
    layer0_kernel<<<256, 512, 0, stream>>>(sidx, trump, b0, W0h, h0);
    mlp_kernel<<<512, 512, 0, stream>>>(h0, W1T, W2T, b1, b2, Wp, bp, legal, out);
}

// Round 5
// 85.544 us; speedup vs baseline: 1.1692x; 1.1692x over previous
//
#include <hip/hip_runtime.h>
#include <hip/hip_bf16.h>

typedef unsigned int u32;
typedef unsigned short u16;
typedef unsigned char u8;
typedef _Float16 f16;
typedef __attribute__((ext_vector_type(2)))  _Float16 f16x2;
typedef __attribute__((ext_vector_type(8)))  _Float16 f16x8;
typedef __attribute__((ext_vector_type(16))) _Float16 f16x16;
typedef __attribute__((ext_vector_type(4))) float f32x4;

#define NSLOT   71
#define NCARD   71
#define ONEHOT  5041     // 71*71
#define INDIM   5048     // 71*71 + 7
#define D0      512
#define D1      256
#define D2      128
#define NACT    9

__device__ __forceinline__ u16 f2h_bits(float x) { f16 h = (f16)x; u16 r; __builtin_memcpy(&r, &h, 2); return r; }

// ---------------- prep: W0 -> f16, W1 -> W1T f16 (N x K), W2 -> W2T f16 ----------------
__global__ void prep_kernel(const float* __restrict__ W0, const float* __restrict__ W1,
                            const float* __restrict__ W2,
                            u16* __restrict__ W0h, u16* __restrict__ W1T, u16* __restrict__ W2T) {
    int i = blockIdx.x * 256 + threadIdx.x;
    const int n0 = INDIM * D0;      // 2,584,576
    const int n1 = D0 * D1;         // 131,072
    const int n2 = D1 * D2;         // 32,768
    if (i < n0) {
        W0h[i] = f2h_bits(W0[i]);
    } else if (i < n0 + n1) {
        int j = i - n0; int n = j >> 9, k = j & 511;     // W1T[n][k] = W1[k][n]
        W1T[j] = f2h_bits(W1[k * D1 + n]);
    } else if (i < n0 + n1 + n2) {
        int j = i - n0 - n1; int n = j >> 8, k = j & 255; // W2T[n][k] = W2[k][n]
        W2T[j] = f2h_bits(W2[k * D2 + n]);
    }
}

// ---------------- layer 0: gather-sum one-hot rows + trump + b0, ReLU, write h0 f16 ----------------
// grid: 512 blocks = (chunk 0..127 slow) x (ct 0..3 fast).  ct = b&3 is XCD-aligned under
// round-robin dispatch (XCD = b%8): all blocks on XCD x share ct = x&3 -> each XCD's L2
// holds one 1.3MB W0 col-slice (R2 evidence: FETCH 15MB vs 22.7/35.6 for other mappings).
// 128 rows/block, 512 threads = 64 rowgrp x 8 colgrp, 2 rows/thread.
// 2 blocks/CU -> 16 waves/CU for latency hiding; per-slot L1 set ~2x15KB <= 32KB L1.
__global__ __launch_bounds__(512)
void layer0_kernel(const int* __restrict__ sidx, const float* __restrict__ trump,
                   const float* __restrict__ b0, const u16* __restrict__ W0h,
                   u16* __restrict__ h0) {
    __shared__ u8 idxl[128 * NSLOT];     // [row][slot]
    __shared__ float trl[128 * 7];       // [row][t]
    const int tid = threadIdx.x;
    const int ct = blockIdx.x & 3;           // fast -> constant per XCD
    const int chunk = blockIdx.x >> 2;       // 0..127
    const int rbase = chunk * 128;

    for (int i = tid; i < 128 * NSLOT; i += 512) {      // coalesced: i = r*71+s
        int v = sidx[rbase * NSLOT + i];
        v = v < 0 ? 0 : (v > NCARD - 1 ? NCARD - 1 : v);
        idxl[i] = (u8)v;
    }
    for (int i = tid; i < 128 * 7; i += 512)
        trl[i] = trump[rbase * 7 + i];
    __syncthreads();

    const int rg = tid >> 3;                 // 0..63
    const int cg = tid & 7;                  // 0..7
    const int c0 = ct * 128 + cg * 16;       // col offset in [0,512)

    f16x16 acc[2];
    {   // init with b0 + trump tail (rows 5041..5047 of W0)
        f16x16 bias;
        #pragma unroll
        for (int j = 0; j < 16; ++j) bias[j] = (f16)b0[c0 + j];
        #pragma unroll
        for (int i = 0; i < 2; ++i) acc[i] = bias;
        #pragma unroll
        for (int t = 0; t < 7; ++t) {
            f16x16 wv = *(const f16x16*)(W0h + (size_t)(ONEHOT + t) * D0 + c0);
            #pragma unroll
            for (int i = 0; i < 2; ++i)
                acc[i] += wv * (f16)trl[(rg * 2 + i) * 7 + t];
        }
    }

    for (int s = 0; s < NSLOT; ++s) {
        const u16* base = W0h + (size_t)s * NCARD * D0 + c0;
        #pragma unroll
        for (int i = 0; i < 2; ++i) {
            int card = idxl[(rg * 2 + i) * NSLOT + s];
            f16x16 wv = *(const f16x16*)(base + ((u32)card << 9));
            acc[i] += wv;                    // 8x v_pk_add_f16
        }
    }

    const f16x16 zero = {};
    #pragma unroll
    for (int i = 0; i < 2; ++i) {
        int row = rbase + rg * 2 + i;
        f16x16 v = __builtin_elementwise_max(acc[i], zero);   // ReLU, packed
        uint4* dst = (uint4*)(h0 + (size_t)row * D0 + c0);
        dst[0] = ((const uint4*)&v)[0];
        dst[1] = ((const uint4*)&v)[1];
    }
}

// ---------------- layers 1,2,p fused: per-block 32 rows, MFMA 16x16x32 f16 ----------------
// grid: 512 blocks x 512 threads (8 waves).  LDS < 64KB.
__global__ __launch_bounds__(512)
void mlp_kernel(const u16* __restrict__ h0, const u16* __restrict__ W1T, const u16* __restrict__ W2T,
                const float* __restrict__ b1, const float* __restrict__ b2,
                const float* __restrict__ Wp, const float* __restrict__ bp,
                const int* __restrict__ legal, float* __restrict__ out) {
    __shared__ u16 Abuf[32 * 520];          // h0 tile, pad 8 (row 1040B)
    __shared__ u16 h1buf[32 * 264];         // pad 8 (528B)
    __shared__ u16 h2buf[32 * 136];         // pad 8 (272B)
    __shared__ float wpb[D2 * NACT + NACT]; // Wp + bp
    const int tid = threadIdx.x;
    const int r0 = blockIdx.x * 32;

    for (int i = tid; i < 2048; i += 512) {             // 32 rows x 64 uint4
        int r = i >> 6, g = i & 63;
        uint4 v = *(const uint4*)(h0 + (size_t)(r0 + r) * D0 + g * 8);
        *(uint4*)&Abuf[r * 520 + g * 8] = v;
    }
    for (int i = tid; i < D2 * NACT + NACT; i += 512)
        wpb[i] = (i < D2 * NACT) ? Wp[i] : bp[i - D2 * NACT];
    __syncthreads();

    const int w  = tid >> 6;     // wave 0..7
    const int l  = tid & 63;
    const int lc = l & 15;       // A row / B col / D col within 16-frag
    const int kg = l >> 4;       // 0..3

    // ---- layer 1: (32x512) @ (512x256), waves split N into 8 x 32 ----
    {
        const int n0 = w * 32;
        f32x4 a00 = {0.f,0.f,0.f,0.f}, a01 = a00, a10 = a00, a11 = a00;
        for (int kb = 0; kb < D0; kb += 32) {
            f16x8 av0 = *(const f16x8*)&Abuf[lc * 520 + kb + kg * 8];
            f16x8 av1 = *(const f16x8*)&Abuf[(lc + 16) * 520 + kb + kg * 8];
            f16x8 bv0 = *(const f16x8*)(W1T + (size_t)(n0 + lc) * D0 + kb + kg * 8);
            f16x8 bv1 = *(const f16x8*)(W1T + (size_t)(n0 + 16 + lc) * D0 + kb + kg * 8);
            a00 = __builtin_amdgcn_mfma_f32_16x16x32_f16(av0, bv0, a00, 0, 0, 0);
            a01 = __builtin_amdgcn_mfma_f32_16x16x32_f16(av0, bv1, a01, 0, 0, 0);
            a10 = __builtin_amdgcn_mfma_f32_16x16x32_f16(av1, bv0, a10, 0, 0, 0);
            a11 = __builtin_amdgcn_mfma_f32_16x16x32_f16(av1, bv1, a11, 0, 0, 0);
        }
        #pragma unroll
        for (int nb = 0; nb < 2; ++nb) {
            int col = n0 + nb * 16 + lc;
            float bias = b1[col];
            #pragma unroll
            for (int j = 0; j < 4; ++j) {
                f32x4 v0 = nb ? a01 : a00;
                f32x4 v1 = nb ? a11 : a10;
                h1buf[(kg * 4 + j) * 264 + col]        = f2h_bits(fmaxf(v0[j] + bias, 0.f));
                h1buf[(16 + kg * 4 + j) * 264 + col]   = f2h_bits(fmaxf(v1[j] + bias, 0.f));
            }
        }
    }
    __syncthreads();

    // ---- layer 2: (32x256) @ (256x128), waves split N into 8 x 16 ----
    {
        const int n0 = w * 16;
        f32x4 c0 = {0.f,0.f,0.f,0.f}, c1 = c0;
        for (int kb = 0; kb < D1; kb += 32) {
            f16x8 av0 = *(const f16x8*)&h1buf[lc * 264 + kb + kg * 8];
            f16x8 av1 = *(const f16x8*)&h1buf[(lc + 16) * 264 + kb + kg * 8];
            f16x8 bv  = *(const f16x8*)(W2T + (size_t)(n0 + lc) * D1 + kb + kg * 8);
            c0 = __builtin_amdgcn_mfma_f32_16x16x32_f16(av0, bv, c0, 0, 0, 0);
            c1 = __builtin_amdgcn_mfma_f32_16x16x32_f16(av1, bv, c1, 0, 0, 0);
        }
        int col = n0 + lc;
        float bias = b2[col];
        #pragma unroll
        for (int j = 0; j < 4; ++j) {
            h2buf[(kg * 4 + j) * 136 + col]      = f2h_bits(fmaxf(c0[j] + bias, 0.f));
            h2buf[(16 + kg * 4 + j) * 136 + col] = f2h_bits(fmaxf(c1[j] + bias, 0.f));
        }
    }
    __syncthreads();

    // ---- layer p + log_softmax: 128 threads, 4 threads per row (K split 4x32) ----
    if (tid < 128) {
        int r = tid >> 2, q = tid & 3;
        float part[NACT];
        #pragma unroll
        for (int a = 0; a < NACT; ++a) part[a] = 0.f;
        int kbase = q * 32;
        #pragma unroll
        for (int kk = 0; kk < 32; kk += 2) {
            u32 pr = *(const u32*)&h2buf[r * 136 + kbase + kk];
            f16x2 hp; __builtin_memcpy(&hp, &pr, 4);
            float x0 = (float)hp.x, x1 = (float)hp.y;
            #pragma unroll
            for (int a = 0; a < NACT; ++a)
                part[a] += x0 * wpb[(kbase + kk) * NACT + a] + x1 * wpb[(kbase + kk + 1) * NACT + a];
        }
        #pragma unroll
        for (int a = 0; a < NACT; ++a) {
            part[a] += __shfl_xor(part[a], 1, 64);
            part[a] += __shfl_xor(part[a], 2, 64);
        }
        if (q == 0) {
            int row = r0 + r;
            const int* mk = legal + (size_t)row * NACT;   // bool uploaded as 4-byte; nonzero = legal
            float lg[NACT]; float mx = -INFINITY;
            #pragma unroll
            for (int a = 0; a < NACT; ++a) {
                lg[a] = part[a] + wpb[D2 * NACT + a];
                if (mk[a] != 0 && lg[a] > mx) mx = lg[a];
            }
            float s = 0.f;
            #pragma unroll
            for (int a = 0; a < NACT; ++a) if (mk[a] != 0) s += __expf(lg[a] - mx);
            float lse = mx + __logf(s);
            #pragma unroll
            for (int a = 0; a < NACT; ++a)
                out[(size_t)row * NACT + a] = (mk[a] != 0) ? (lg[a] - lse) : -INFINITY;
        }
    }
}

extern "C" void kernel_launch(void* const* d_in, const int* in_sizes, int n_in,
                              void* d_out, int out_size, void* d_ws, size_t ws_size,
                              hipStream_t stream) {
    const int*   sidx  = (const int*)d_in[0];
    const float* trump = (const float*)d_in[1];
    const int*   legal = (const int*)d_in[2];
    const float* W0 = (const float*)d_in[3];
    const float* b0 = (const float*)d_in[4];
    const float* W1 = (const float*)d_in[5];
    const float* b1 = (const float*)d_in[6];
    const float* W2 = (const float*)d_in[7];
    const float* b2 = (const float*)d_in[8];
    const float* Wp = (const float*)d_in[9];
    const float* bp = (const float*)d_in[10];
    float* out = (float*)d_out;

    // ws layout (f16 elements): W0h | W1T | W2T | h0   -> 22.3 MB total
    u16* W0h  = (u16*)d_ws;
    u16* W1T  = W0h + (size_t)INDIM * D0;
    u16* W2T  = W1T + (size_t)D0 * D1;
    u16* h0   = W2T + (size_t)D1 * D2;

    const int total = INDIM * D0 + D0 * D1 + D1 * D2;   // 2,748,416
    prep_kernel<<<(total + 255) / 256, 256, 0, stream>>>(W0, W1, W2, W0h, W1T, W2T);
    layer0_kernel<<<512, 512, 0, stream>>>(sidx, trump, b0, W0h, h0);
    mlp_kernel<<<512, 512, 0, stream>>>(h0, W1T, W2T, b1, b2, Wp, bp, legal, out);
}